// Round 10
// baseline (62.593 us; speedup 1.0000x reference)
//
#include <hip/hip_runtime.h>
#include <hip/hip_bf16.h>
#include <stdint.h>

#define B_ 4
#define S_ 4096
#define D_ 1024
#define TOPK_ 2048
#define NSEL_ (S_ - TOPK_)

// GEMM geometry (validated round-4 structure): 128x128 tile, BK=64, 8 waves 32x64
#define BM 128
#define BN 128
#define BK 64
#define NT (D_ / BK)  // 16
#define GEMM_BLOCKS (B_ * (TOPK_ / BM) * (D_ / BN))  // 512

// k_prep grid segments
#define PREP_CONV (B_ * TOPK_)              // 8192 blocks: selected-row fp32->bf16 compact
#define PREP_COPY (B_ * NSEL_)              // 8192 blocks: complement-row out=x copy
#define PREP_W    (D_ * D_ / 1024)          // 1024 blocks: W fp32->bf16

typedef __attribute__((ext_vector_type(8))) short bf16x8;
typedef __attribute__((ext_vector_type(4))) float f32x4;

__device__ __forceinline__ unsigned pack2bf16(float a, float b) {
  unsigned ua = __float_as_uint(a);
  unsigned ub = __float_as_uint(b);
  ua += 0x7fffu + ((ua >> 16) & 1u);
  ub += 0x7fffu + ((ub >> 16) & 1u);
  return (ua >> 16) | (ub & 0xffff0000u);
}

__device__ __forceinline__ unsigned mono_u32(float f) {
  unsigned u = __float_as_uint(f);
  return (u & 0x80000000u) ? ~u : (u | 0x80000000u);
}

__device__ __forceinline__ void gload_lds16(const void* g, void* l) {
  __builtin_amdgcn_global_load_lds(
      (const __attribute__((address_space(1))) void*)g,
      (__attribute__((address_space(3))) void*)l, 16, 0, 0);
}

// ---------------- K1: router logits only ----------------
__global__ __launch_bounds__(256) void k_router_logits(
    const float* __restrict__ x, const float* __restrict__ wr,
    float* __restrict__ logits) {
  const int lane = threadIdx.x & 63;
  const int token = blockIdx.x * 4 + (threadIdx.x >> 6);
  const float4* xr = (const float4*)(x + (size_t)token * D_);
  const float4* wrow = (const float4*)wr;
  double acc = 0.0;
#pragma unroll
  for (int i = 0; i < 4; ++i) {
    float4 v = xr[i * 64 + lane];
    float4 w = wrow[i * 64 + lane];
    acc += (double)v.x * (double)w.x + (double)v.y * (double)w.y +
           (double)v.z * (double)w.z + (double)v.w * (double)w.w;
  }
#pragma unroll
  for (int off = 32; off; off >>= 1) acc += __shfl_down(acc, off);
  if (lane == 0) logits[token] = (float)acc;
}

// ---------------- K2: exact top-k via 4-pass radix select ----------------
__global__ __launch_bounds__(1024) void k_select(
    const float* __restrict__ logits, unsigned* __restrict__ sel,
    unsigned* __restrict__ notsel) {
  __shared__ unsigned hist[256];
  __shared__ unsigned bc_digit, bc_need;
  __shared__ unsigned scanbuf[17];

  const int b = blockIdx.x;
  const int tid = threadIdx.x;
  const int lane = tid & 63;
  const int wave = tid >> 6;

  float4 v = *(const float4*)(logits + b * S_ + tid * 4);
  unsigned k0 = mono_u32(v.x), k1 = mono_u32(v.y),
           k2 = mono_u32(v.z), k3 = mono_u32(v.w);

  unsigned prefix = 0, need = TOPK_;
#pragma unroll
  for (int pass = 0; pass < 4; ++pass) {
    const int shift = 24 - pass * 8;
    const unsigned maskhi = pass ? (0xFFFFFFFFu << (shift + 8)) : 0u;
    if (tid < 256) hist[tid] = 0;
    __syncthreads();
    if ((k0 & maskhi) == prefix) atomicAdd(&hist[(k0 >> shift) & 255], 1u);
    if ((k1 & maskhi) == prefix) atomicAdd(&hist[(k1 >> shift) & 255], 1u);
    if ((k2 & maskhi) == prefix) atomicAdd(&hist[(k2 >> shift) & 255], 1u);
    if ((k3 & maskhi) == prefix) atomicAdd(&hist[(k3 >> shift) & 255], 1u);
    __syncthreads();
    if (wave == 0) {
      uint4 h = *(const uint4*)(hist + lane * 4);
      unsigned t = h.x + h.y + h.z + h.w;
      unsigned inc = t;
#pragma unroll
      for (int off = 1; off < 64; off <<= 1) {
        unsigned u = __shfl_up(inc, off);
        if (lane >= off) inc += u;
      }
      unsigned total = __shfl(inc, 63);
      unsigned above = total - inc;
      unsigned a3 = above;
      unsigned a2 = a3 + h.w;
      unsigned a1 = a2 + h.z;
      unsigned a0 = a1 + h.y;
      if (a3 < need && need <= a3 + h.w) { bc_digit = lane * 4 + 3; bc_need = need - a3; }
      else if (a2 < need && need <= a2 + h.z) { bc_digit = lane * 4 + 2; bc_need = need - a2; }
      else if (a1 < need && need <= a1 + h.y) { bc_digit = lane * 4 + 1; bc_need = need - a1; }
      else if (a0 < need && need <= a0 + h.x) { bc_digit = lane * 4 + 0; bc_need = need - a0; }
    }
    __syncthreads();
    prefix |= bc_digit << shift;
    need = bc_need;
  }

  const unsigned V = prefix;
  const unsigned fneed = need;

  unsigned packed = 0;
  unsigned pk_excl0, pk_excl1, pk_excl2, pk_excl3;
  pk_excl0 = packed; if (k0 > V) packed += 1u << 16; else if (k0 == V) packed += 1u;
  pk_excl1 = packed; if (k1 > V) packed += 1u << 16; else if (k1 == V) packed += 1u;
  pk_excl2 = packed; if (k2 > V) packed += 1u << 16; else if (k2 == V) packed += 1u;
  pk_excl3 = packed; if (k3 > V) packed += 1u << 16; else if (k3 == V) packed += 1u;

  unsigned inc = packed;
#pragma unroll
  for (int off = 1; off < 64; off <<= 1) {
    unsigned u = __shfl_up(inc, off);
    if (lane >= off) inc += u;
  }
  if (lane == 63) scanbuf[wave] = inc;
  __syncthreads();
  if (tid < 16) {
    unsigned t = scanbuf[tid];
    unsigned winc = t;
#pragma unroll
    for (int off = 1; off < 16; off <<= 1) {
      unsigned u = __shfl_up(winc, off);
      if (tid >= off) winc += u;
    }
    scanbuf[tid] = winc - t;
    if (tid == 15) scanbuf[16] = winc;
  }
  __syncthreads();
  const unsigned base = scanbuf[wave] + (inc - packed);
  const unsigned G_total = scanbuf[16] >> 16;

  unsigned* selb = sel + b * TOPK_;
  unsigned* notb = notsel + b * NSEL_;
#pragma unroll
  for (int i = 0; i < 4; ++i) {
    unsigned ki = (i == 0) ? k0 : (i == 1) ? k1 : (i == 2) ? k2 : k3;
    unsigned pe = (i == 0) ? pk_excl0 : (i == 1) ? pk_excl1 : (i == 2) ? pk_excl2 : pk_excl3;
    unsigned s = tid * 4 + i;
    unsigned gtE = (base + pe) >> 16;
    unsigned eqE = (base + pe) & 0xFFFFu;
    if (ki > V) {
      selb[gtE] = s;
    } else if (ki == V && eqE < fneed) {
      selb[G_total + eqE] = s;
    } else {
      unsigned eqTaken = (eqE < fneed) ? eqE : fneed;
      notb[s - gtE - eqTaken] = s;
    }
  }
}

// ---------------- K3: prep — compact-convert selected rows, copy complement, W->bf16 ----------------
// x is L3-resident after the router pass, so reads here are ~free of HBM.
__global__ __launch_bounds__(256) void k_prep(
    const float* __restrict__ x, const unsigned* __restrict__ sel,
    const unsigned* __restrict__ notsel, const float* __restrict__ wblock,
    unsigned short* __restrict__ xbfc, unsigned short* __restrict__ wbf,
    float* __restrict__ out) {
  const int bid = blockIdx.x;
  const int tid = threadIdx.x;

  if (bid < PREP_CONV) {
    // convert selected row -> compact bf16 row
    const int b = bid >> 11;  // TOPK_ == 2048
    const unsigned srow = sel[bid];
    const float4* src = (const float4*)(x + ((size_t)b * S_ + srow) * D_);
    float4 v = src[tid];
    *(uint2*)(xbfc + (size_t)bid * D_ + tid * 4) =
        make_uint2(pack2bf16(v.x, v.y), pack2bf16(v.z, v.w));
    return;
  }
  if (bid < PREP_CONV + PREP_COPY) {
    // copy complement row to out
    const int r = bid - PREP_CONV;
    const int b = r >> 11;  // NSEL_ == 2048
    const unsigned s = notsel[r];
    const size_t off = ((size_t)b * S_ + s) * D_;
    ((float4*)(out + off))[tid] = ((const float4*)(x + off))[tid];
    return;
  }
  // W fp32 -> bf16
  const int i = (bid - PREP_CONV - PREP_COPY) * 256 + tid;
  float4 v = ((const float4*)wblock)[i];
  *(uint2*)(wbf + (size_t)i * 4) =
      make_uint2(pack2bf16(v.x, v.y), pack2bf16(v.z, v.w));
}

// ---------------- K4: pure GEMM (round-4 validated structure, compact A) ----------------
// C[m,e] = sum_d xbfc[b*TOPK+ m, d] * W[e, d]; scatter rows via sel in epilogue.
__global__ __launch_bounds__(512, 2) void k_gemm(
    const unsigned short* __restrict__ xbfc, const unsigned short* __restrict__ wbf,
    const unsigned* __restrict__ sel, float* __restrict__ out) {
  __shared__ __align__(16) unsigned short Alds[2][BM * BK];  // 32 KB
  __shared__ __align__(16) unsigned short Blds[2][BN * BK];  // 32 KB

  const int bid = blockIdx.x;
  const int tid = threadIdx.x;

  // XCD-aware swizzle: XCD = bid&7 owns 8 contiguous M-panels x all 8 N-tiles.
  const int gtile = (bid & 7) * 64 + (bid >> 3);
  const int mtile = gtile >> 3;
  const int nb = gtile & 7;
  const int b = mtile >> 4;
  const int mb = mtile & 15;

  const unsigned* selb = sel + b * TOPK_;
  const unsigned short* arows = xbfc + ((size_t)b * TOPK_ + mb * BM) * D_;
  float* outb = out + (size_t)b * S_ * D_;

  const int lane = tid & 63;
  const int wid = tid >> 6;
  const int wm = wid >> 1;
  const int wn = wid & 1;

  // staging: 1024 16B-chunks per operand; thread covers chunks {tid, tid+512};
  // linear LDS dest, inverse-swizzled per-lane global source (rule #21).
  const unsigned short* asrc[2];
  const unsigned short* bsrc[2];
  unsigned ldsoff[2];
#pragma unroll
  for (int r = 0; r < 2; ++r) {
    int chunk = r * 512 + tid;
    int row = chunk >> 3, c16 = chunk & 7;
    int sw = c16 ^ (row & 7);
    asrc[r] = arows + (size_t)row * D_ + sw * 8;           // compact rows, no gather
    bsrc[r] = wbf + (size_t)(nb * BN + row) * D_ + sw * 8;
    ldsoff[r] = chunk * 16;
  }

  // compute-side swizzled ds_read byte offsets
  unsigned aoff[2][2], boff[4][2];
#pragma unroll
  for (int mi = 0; mi < 2; ++mi)
#pragma unroll
    for (int kk = 0; kk < 2; ++kk) {
      int rrow = wm * 32 + mi * 16 + (lane & 15);
      int byte = rrow * 128 + kk * 64 + (lane >> 4) * 16;
      aoff[mi][kk] = byte ^ ((rrow & 7) << 4);
    }
#pragma unroll
  for (int nj = 0; nj < 4; ++nj)
#pragma unroll
    for (int kk = 0; kk < 2; ++kk) {
      int rrow = wn * 64 + nj * 16 + (lane & 15);
      int byte = rrow * 128 + kk * 64 + (lane >> 4) * 16;
      boff[nj][kk] = byte ^ ((rrow & 7) << 4);
    }

  f32x4 acc[2][4];
#pragma unroll
  for (int i = 0; i < 2; ++i)
#pragma unroll
    for (int j = 0; j < 4; ++j) acc[i][j] = (f32x4)0.0f;

  // prologue: stage tile 0 into buf 0
#pragma unroll
  for (int r = 0; r < 2; ++r) {
    gload_lds16(asrc[r], (char*)&Alds[0][0] + ldsoff[r]);
    gload_lds16(bsrc[r], (char*)&Blds[0][0] + ldsoff[r]);
  }
  __syncthreads();

  int cur = 0;
  for (int t = 0; t < NT; ++t) {
    if (t + 1 < NT) {
      const int koff = (t + 1) * BK;
#pragma unroll
      for (int r = 0; r < 2; ++r) {
        gload_lds16(asrc[r] + koff, (char*)&Alds[cur ^ 1][0] + ldsoff[r]);
        gload_lds16(bsrc[r] + koff, (char*)&Blds[cur ^ 1][0] + ldsoff[r]);
      }
    }
#pragma unroll
    for (int kk = 0; kk < 2; ++kk) {
      bf16x8 af[2], bfr[4];
#pragma unroll
      for (int mi = 0; mi < 2; ++mi)
        af[mi] = *(const bf16x8*)((const char*)&Alds[cur][0] + aoff[mi][kk]);
#pragma unroll
      for (int nj = 0; nj < 4; ++nj)
        bfr[nj] = *(const bf16x8*)((const char*)&Blds[cur][0] + boff[nj][kk]);
#pragma unroll
      for (int mi = 0; mi < 2; ++mi)
#pragma unroll
        for (int nj = 0; nj < 4; ++nj)
          acc[mi][nj] = __builtin_amdgcn_mfma_f32_16x16x32_bf16(af[mi], bfr[nj], acc[mi][nj], 0, 0, 0);
    }
    __syncthreads();  // drains vmcnt (staged loads) + lgkm; protects dbuf swap
    cur ^= 1;
  }

  // epilogue: scatter C rows via sel
#pragma unroll
  for (int mi = 0; mi < 2; ++mi) {
#pragma unroll
    for (int j = 0; j < 4; ++j) {
      int m = mb * BM + wm * 32 + mi * 16 + (lane >> 4) * 4 + j;
      unsigned srow = selb[m];
      float* orow = outb + (size_t)srow * D_;
#pragma unroll
      for (int nj = 0; nj < 4; ++nj) {
        int col = nb * BN + wn * 64 + nj * 16 + (lane & 15);
        orow[col] = acc[mi][nj][j];
      }
    }
  }
}

// ---------------- fallback: reg-staged GEMM + separate copy ----------------
__global__ __launch_bounds__(256) void k_copy_rows(
    const float* __restrict__ x, const unsigned* __restrict__ notsel,
    float* __restrict__ out) {
  const int r = blockIdx.x;
  const int b = r >> 11;
  const unsigned s = notsel[r];
  const size_t off = ((size_t)b * S_ + s) * D_;
  ((float4*)(out + off))[threadIdx.x] = ((const float4*)(x + off))[threadIdx.x];
}

__global__ __launch_bounds__(512) void k_gemm_reg(
    const float* __restrict__ x, const float* __restrict__ w,
    const unsigned* __restrict__ sel, float* __restrict__ out) {
  __shared__ __align__(16) unsigned short Alds[BM * BK];
  __shared__ __align__(16) unsigned short Blds[BN * BK];

  const int bid = blockIdx.x;
  const int b = bid >> 7;
  const int rem = bid & 127;
  const int mb = rem >> 3;
  const int nb = rem & 7;

  const unsigned* selb = sel + b * TOPK_;
  const float* xb = x + (size_t)b * S_ * D_;
  float* outb = out + (size_t)b * S_ * D_;

  const int tid = threadIdx.x;
  const int lane = tid & 63;
  const int wid = tid >> 6;
  const int wm = wid >> 1;
  const int wn = wid & 1;

  const float* asrc[4];
  const float* bsrc[4];
  int srow_[4], sc4_[4];
#pragma unroll
  for (int r = 0; r < 4; ++r) {
    int flat = r * 512 + tid;
    int row = flat >> 4;
    int c4 = flat & 15;
    srow_[r] = row;
    sc4_[r] = c4;
    asrc[r] = xb + (size_t)selb[mb * BM + row] * D_ + c4 * 4;
    bsrc[r] = w + (size_t)(nb * BN + row) * D_ + c4 * 4;
  }

  f32x4 acc[2][4];
#pragma unroll
  for (int i = 0; i < 2; ++i)
#pragma unroll
    for (int j = 0; j < 4; ++j) acc[i][j] = (f32x4)0.0f;

  float4 pa[4], pb[4];
#pragma unroll
  for (int r = 0; r < 4; ++r) {
    pa[r] = *(const float4*)(asrc[r]);
    pb[r] = *(const float4*)(bsrc[r]);
  }

  for (int t = 0; t < NT; ++t) {
#pragma unroll
    for (int r = 0; r < 4; ++r) {
      int row = srow_[r], c4 = sc4_[r];
      int byte = row * 128 + c4 * 8;
      byte ^= (row & 7) << 4;
      *(uint2*)((char*)Alds + byte) = make_uint2(pack2bf16(pa[r].x, pa[r].y), pack2bf16(pa[r].z, pa[r].w));
      *(uint2*)((char*)Blds + byte) = make_uint2(pack2bf16(pb[r].x, pb[r].y), pack2bf16(pb[r].z, pb[r].w));
    }
    __syncthreads();

    if (t + 1 < NT) {
      const int koff = (t + 1) * BK;
#pragma unroll
      for (int r = 0; r < 4; ++r) {
        pa[r] = *(const float4*)(asrc[r] + koff);
        pb[r] = *(const float4*)(bsrc[r] + koff);
      }
    }

#pragma unroll
    for (int kk = 0; kk < 2; ++kk) {
      bf16x8 af[2], bfr[4];
#pragma unroll
      for (int mi = 0; mi < 2; ++mi) {
        int rrow = wm * 32 + mi * 16 + (lane & 15);
        int byte = rrow * 128 + (kk * 32 + (lane >> 4) * 8) * 2;
        byte ^= (rrow & 7) << 4;
        af[mi] = *(const bf16x8*)((const char*)Alds + byte);
      }
#pragma unroll
      for (int nj = 0; nj < 4; ++nj) {
        int rrow = wn * 64 + nj * 16 + (lane & 15);
        int byte = rrow * 128 + (kk * 32 + (lane >> 4) * 8) * 2;
        byte ^= (rrow & 7) << 4;
        bfr[nj] = *(const bf16x8*)((const char*)Blds + byte);
      }
#pragma unroll
      for (int mi = 0; mi < 2; ++mi)
#pragma unroll
        for (int nj = 0; nj < 4; ++nj)
          acc[mi][nj] = __builtin_amdgcn_mfma_f32_16x16x32_bf16(af[mi], bfr[nj], acc[mi][nj], 0, 0, 0);
    }
    __syncthreads();
  }

#pragma unroll
  for (int mi = 0; mi < 2; ++mi) {
#pragma unroll
    for (int j = 0; j < 4; ++j) {
      int m = mb * BM + wm * 32 + mi * 16 + (lane >> 4) * 4 + j;
      unsigned srow = selb[m];
      float* orow = outb + (size_t)srow * D_;
#pragma unroll
      for (int nj = 0; nj < 4; ++nj) {
        int col = nb * BN + wn * 64 + nj * 16 + (lane & 15);
        orow[col] = acc[mi][nj][j];
      }
    }
  }
}

extern "C" void kernel_launch(void* const* d_in, const int* in_sizes, int n_in,
                              void* d_out, int out_size, void* d_ws, size_t ws_size,
                              hipStream_t stream) {
  (void)in_sizes; (void)n_in; (void)out_size;
  const float* x = (const float*)d_in[0];
  const float* wb = (const float*)d_in[1];
  const float* wr = (const float*)d_in[2];
  float* out = (float*)d_out;

  char* ws = (char*)d_ws;
  float* logits = (float*)ws;                                   // 64 KB
  unsigned* sel = (unsigned*)(ws + 65536);                      // 32 KB
  unsigned* notsel = sel + (size_t)B_ * TOPK_;                  // 32 KB -> 128 KB
  unsigned short* xbfc = (unsigned short*)(ws + 131072);        // B*TOPK*D*2 = 16.78 MB
  unsigned short* wbf = (unsigned short*)(ws + 131072 + (size_t)B_ * TOPK_ * D_ * 2);  // 2 MB
  const size_t NEED = 131072 + (size_t)B_ * TOPK_ * D_ * 2 + (size_t)D_ * D_ * 2;
  const bool fast = ws_size >= NEED;

  if (fast) {
    k_router_logits<<<B_ * S_ / 4, 256, 0, stream>>>(x, wr, logits);
    k_select<<<B_, 1024, 0, stream>>>(logits, sel, notsel);
    k_prep<<<PREP_CONV + PREP_COPY + PREP_W, 256, 0, stream>>>(x, sel, notsel, wb, xbfc, wbf, out);
    k_gemm<<<GEMM_BLOCKS, 512, 0, stream>>>(xbfc, wbf, sel, out);
  } else {
    k_router_logits<<<B_ * S_ / 4, 256, 0, stream>>>(x, wr, logits);
    k_select<<<B_, 1024, 0, stream>>>(logits, sel, notsel);
    k_copy_rows<<<B_ * NSEL_, 256, 0, stream>>>(x, notsel, out);
    k_gemm_reg<<<GEMM_BLOCKS, 512, 0, stream>>>(x, wb, sel, out);
  }
}

// Round 11
// 62.411 us; speedup vs baseline: 1.0029x; 1.0029x over previous
//
#include <hip/hip_runtime.h>
#include <hip/hip_bf16.h>
#include <stdint.h>

#define B_ 4
#define S_ 4096
#define D_ 1024
#define TOPK_ 2048
#define NSEL_ (S_ - TOPK_)

#define BM 128
#define BN 128
#define BK 64
#define NT (D_ / BK)       // 16
#define GEMM_BLOCKS (B_ * (TOPK_ / BM) * (D_ / BN))  // 512
#define COPY_BLOCKS (B_ * NSEL_ / 2)                 // 4096 (2 rows each)

typedef __attribute__((ext_vector_type(8))) short bf16x8;
typedef __attribute__((ext_vector_type(4))) float f32x4;

// RNE fp32 -> bf16 pack (two floats -> one u32, low|high)
__device__ __forceinline__ unsigned pack2bf16(float a, float b) {
  unsigned ua = __float_as_uint(a);
  unsigned ub = __float_as_uint(b);
  ua += 0x7fffu + ((ua >> 16) & 1u);
  ub += 0x7fffu + ((ub >> 16) & 1u);
  return (ua >> 16) | (ub & 0xffff0000u);
}

__device__ __forceinline__ unsigned mono_u32(float f) {
  unsigned u = __float_as_uint(f);
  return (u & 0x80000000u) ? ~u : (u | 0x80000000u);
}

__device__ __forceinline__ void gload_lds16(const void* g, void* l) {
  __builtin_amdgcn_global_load_lds(
      (const __attribute__((address_space(1))) void*)g,
      (__attribute__((address_space(3))) void*)l, 16, 0, 0);
}

// ---------------- K1: router logits + x->bf16, tail blocks do W->bf16 ----------------
__global__ __launch_bounds__(256) void k_router_fused(
    const float* __restrict__ x, const float* __restrict__ wr,
    float* __restrict__ logits, unsigned short* __restrict__ xbf,
    const float* __restrict__ wblock, unsigned short* __restrict__ wbf) {
  const int bid = blockIdx.x;
  if (bid >= B_ * S_ / 4) {
    // W fp32 -> bf16: 1024 blocks x 256 thr x 4 floats = D*D
    const int i = (bid - B_ * S_ / 4) * 256 + threadIdx.x;
    float4 v = ((const float4*)wblock)[i];
    *(uint2*)(wbf + (size_t)i * 4) =
        make_uint2(pack2bf16(v.x, v.y), pack2bf16(v.z, v.w));
    return;
  }
  const int lane = threadIdx.x & 63;
  const int token = bid * 4 + (threadIdx.x >> 6);
  const float4* xr = (const float4*)(x + (size_t)token * D_);
  const float4* wrow = (const float4*)wr;
  double acc = 0.0;
#pragma unroll
  for (int i = 0; i < 4; ++i) {
    float4 v = xr[i * 64 + lane];
    float4 w = wrow[i * 64 + lane];
    uint2 p = make_uint2(pack2bf16(v.x, v.y), pack2bf16(v.z, v.w));
    *(uint2*)(xbf + (size_t)token * D_ + i * 256 + lane * 4) = p;
    acc += (double)v.x * (double)w.x + (double)v.y * (double)w.y +
           (double)v.z * (double)w.z + (double)v.w * (double)w.w;
  }
#pragma unroll
  for (int off = 32; off; off >>= 1) acc += __shfl_down(acc, off);
  if (lane == 0) logits[token] = (float)acc;
}

// fallback router (no bf16 staging)
__global__ __launch_bounds__(256) void k_router_plain(
    const float* __restrict__ x, const float* __restrict__ wr,
    float* __restrict__ logits) {
  const int lane = threadIdx.x & 63;
  const int token = blockIdx.x * 4 + (threadIdx.x >> 6);
  const float4* xr = (const float4*)(x + (size_t)token * D_);
  const float4* wrow = (const float4*)wr;
  double acc = 0.0;
#pragma unroll
  for (int i = 0; i < 4; ++i) {
    float4 v = xr[i * 64 + lane];
    float4 w = wrow[i * 64 + lane];
    acc += (double)v.x * (double)w.x + (double)v.y * (double)w.y +
           (double)v.z * (double)w.z + (double)v.w * (double)w.w;
  }
#pragma unroll
  for (int off = 32; off; off >>= 1) acc += __shfl_down(acc, off);
  if (lane == 0) logits[token] = (float)acc;
}

// ---------------- K2: exact top-k via 4-pass radix select ----------------
__global__ __launch_bounds__(1024) void k_select(
    const float* __restrict__ logits, unsigned* __restrict__ sel,
    unsigned* __restrict__ notsel) {
  __shared__ unsigned hist[256];
  __shared__ unsigned bc_digit, bc_need;
  __shared__ unsigned scanbuf[17];

  const int b = blockIdx.x;
  const int tid = threadIdx.x;
  const int lane = tid & 63;
  const int wave = tid >> 6;

  float4 v = *(const float4*)(logits + b * S_ + tid * 4);
  unsigned k0 = mono_u32(v.x), k1 = mono_u32(v.y),
           k2 = mono_u32(v.z), k3 = mono_u32(v.w);

  unsigned prefix = 0, need = TOPK_;
#pragma unroll
  for (int pass = 0; pass < 4; ++pass) {
    const int shift = 24 - pass * 8;
    const unsigned maskhi = pass ? (0xFFFFFFFFu << (shift + 8)) : 0u;
    if (tid < 256) hist[tid] = 0;
    __syncthreads();
    if ((k0 & maskhi) == prefix) atomicAdd(&hist[(k0 >> shift) & 255], 1u);
    if ((k1 & maskhi) == prefix) atomicAdd(&hist[(k1 >> shift) & 255], 1u);
    if ((k2 & maskhi) == prefix) atomicAdd(&hist[(k2 >> shift) & 255], 1u);
    if ((k3 & maskhi) == prefix) atomicAdd(&hist[(k3 >> shift) & 255], 1u);
    __syncthreads();
    if (wave == 0) {
      uint4 h = *(const uint4*)(hist + lane * 4);
      unsigned t = h.x + h.y + h.z + h.w;
      unsigned inc = t;
#pragma unroll
      for (int off = 1; off < 64; off <<= 1) {
        unsigned u = __shfl_up(inc, off);
        if (lane >= off) inc += u;
      }
      unsigned total = __shfl(inc, 63);
      unsigned above = total - inc;
      unsigned a3 = above;
      unsigned a2 = a3 + h.w;
      unsigned a1 = a2 + h.z;
      unsigned a0 = a1 + h.y;
      if (a3 < need && need <= a3 + h.w) { bc_digit = lane * 4 + 3; bc_need = need - a3; }
      else if (a2 < need && need <= a2 + h.z) { bc_digit = lane * 4 + 2; bc_need = need - a2; }
      else if (a1 < need && need <= a1 + h.y) { bc_digit = lane * 4 + 1; bc_need = need - a1; }
      else if (a0 < need && need <= a0 + h.x) { bc_digit = lane * 4 + 0; bc_need = need - a0; }
    }
    __syncthreads();
    prefix |= bc_digit << shift;
    need = bc_need;
  }

  const unsigned V = prefix;
  const unsigned fneed = need;

  unsigned packed = 0;
  unsigned pk_excl0, pk_excl1, pk_excl2, pk_excl3;
  pk_excl0 = packed; if (k0 > V) packed += 1u << 16; else if (k0 == V) packed += 1u;
  pk_excl1 = packed; if (k1 > V) packed += 1u << 16; else if (k1 == V) packed += 1u;
  pk_excl2 = packed; if (k2 > V) packed += 1u << 16; else if (k2 == V) packed += 1u;
  pk_excl3 = packed; if (k3 > V) packed += 1u << 16; else if (k3 == V) packed += 1u;

  unsigned inc = packed;
#pragma unroll
  for (int off = 1; off < 64; off <<= 1) {
    unsigned u = __shfl_up(inc, off);
    if (lane >= off) inc += u;
  }
  if (lane == 63) scanbuf[wave] = inc;
  __syncthreads();
  if (tid < 16) {
    unsigned t = scanbuf[tid];
    unsigned winc = t;
#pragma unroll
    for (int off = 1; off < 16; off <<= 1) {
      unsigned u = __shfl_up(winc, off);
      if (tid >= off) winc += u;
    }
    scanbuf[tid] = winc - t;
    if (tid == 15) scanbuf[16] = winc;
  }
  __syncthreads();
  const unsigned base = scanbuf[wave] + (inc - packed);
  const unsigned G_total = scanbuf[16] >> 16;

  unsigned* selb = sel + b * TOPK_;
  unsigned* notb = notsel + b * NSEL_;
#pragma unroll
  for (int i = 0; i < 4; ++i) {
    unsigned ki = (i == 0) ? k0 : (i == 1) ? k1 : (i == 2) ? k2 : k3;
    unsigned pe = (i == 0) ? pk_excl0 : (i == 1) ? pk_excl1 : (i == 2) ? pk_excl2 : pk_excl3;
    unsigned s = tid * 4 + i;
    unsigned gtE = (base + pe) >> 16;
    unsigned eqE = (base + pe) & 0xFFFFu;
    if (ki > V) {
      selb[gtE] = s;
    } else if (ki == V && eqE < fneed) {
      selb[G_total + eqE] = s;
    } else {
      unsigned eqTaken = (eqE < fneed) ? eqE : fneed;
      notb[s - gtE - eqTaken] = s;
    }
  }
}

// ---------------- K3 (fast): fused complement-copy + GEMM ----------------
// Round-4 validated kernel with one change: COPY blocks take the LOW block
// IDs (dispatch first). The HBM-write-bound copies drain while GEMM blocks
// fill freed slots, instead of trailing serially after all GEMM blocks.
__global__ __launch_bounds__(512) void k_gemm_copy(
    const unsigned short* __restrict__ xbf, const unsigned short* __restrict__ wbf,
    const unsigned* __restrict__ sel, const unsigned* __restrict__ notsel,
    const float* __restrict__ x, float* __restrict__ out) {
  __shared__ __align__(16) unsigned short Alds[2][BM * BK];
  __shared__ __align__(16) unsigned short Blds[2][BN * BK];

  const int bid = blockIdx.x;
  const int tid = threadIdx.x;

  if (bid < COPY_BLOCKS) {
    // ---- copy path: 2 non-selected rows per block (tid>>8 selects row)
    const int r = bid * 2 + (tid >> 8);  // 0..B_*NSEL_-1
    const int b = r >> 11;               // NSEL_ == 2048
    const unsigned s = notsel[r];
    const size_t off = ((size_t)b * S_ + s) * D_;
    ((float4*)(out + off))[tid & 255] = ((const float4*)(x + off))[tid & 255];
    return;
  }

  // ---- GEMM path (block IDs after the copies)
  const int gbid = bid - COPY_BLOCKS;
  // XCD-aware swizzle: XCD = gbid&7 owns 8 contiguous M-panels x all 8 N-tiles.
  const int gtile = (gbid & 7) * 64 + (gbid >> 3);
  const int mtile = gtile >> 3;
  const int nb = gtile & 7;
  const int b = mtile >> 4;
  const int mb = mtile & 15;

  const unsigned* selb = sel + b * TOPK_;
  const unsigned short* xb = xbf + (size_t)b * S_ * D_;
  float* outb = out + (size_t)b * S_ * D_;

  const int lane = tid & 63;
  const int wid = tid >> 6;
  const int wm = wid >> 1;
  const int wn = wid & 1;

  const unsigned short* asrc[2];
  const unsigned short* bsrc[2];
  unsigned ldsoff[2];
#pragma unroll
  for (int r = 0; r < 2; ++r) {
    int chunk = r * 512 + tid;
    int row = chunk >> 3, c16 = chunk & 7;
    int sw = c16 ^ (row & 7);  // inverse swizzle on source, linear LDS dest
    asrc[r] = xb + (size_t)selb[mb * BM + row] * D_ + sw * 8;
    bsrc[r] = wbf + (size_t)(nb * BN + row) * D_ + sw * 8;
    ldsoff[r] = chunk * 16;
  }

  unsigned aoff[2][2], boff[4][2];
#pragma unroll
  for (int mi = 0; mi < 2; ++mi)
#pragma unroll
    for (int kk = 0; kk < 2; ++kk) {
      int rrow = wm * 32 + mi * 16 + (lane & 15);
      int byte = rrow * 128 + kk * 64 + (lane >> 4) * 16;
      aoff[mi][kk] = byte ^ ((rrow & 7) << 4);
    }
#pragma unroll
  for (int nj = 0; nj < 4; ++nj)
#pragma unroll
    for (int kk = 0; kk < 2; ++kk) {
      int rrow = wn * 64 + nj * 16 + (lane & 15);
      int byte = rrow * 128 + kk * 64 + (lane >> 4) * 16;
      boff[nj][kk] = byte ^ ((rrow & 7) << 4);
    }

  f32x4 acc[2][4];
#pragma unroll
  for (int i = 0; i < 2; ++i)
#pragma unroll
    for (int j = 0; j < 4; ++j) acc[i][j] = (f32x4)0.0f;

#pragma unroll
  for (int r = 0; r < 2; ++r) {
    gload_lds16(asrc[r], (char*)&Alds[0][0] + ldsoff[r]);
    gload_lds16(bsrc[r], (char*)&Blds[0][0] + ldsoff[r]);
  }
  __syncthreads();

  int cur = 0;
  for (int t = 0; t < NT; ++t) {
    if (t + 1 < NT) {
      const int koff = (t + 1) * BK;
#pragma unroll
      for (int r = 0; r < 2; ++r) {
        gload_lds16(asrc[r] + koff, (char*)&Alds[cur ^ 1][0] + ldsoff[r]);
        gload_lds16(bsrc[r] + koff, (char*)&Blds[cur ^ 1][0] + ldsoff[r]);
      }
    }
#pragma unroll
    for (int kk = 0; kk < 2; ++kk) {
      bf16x8 af[2], bfr[4];
#pragma unroll
      for (int mi = 0; mi < 2; ++mi)
        af[mi] = *(const bf16x8*)((const char*)&Alds[cur][0] + aoff[mi][kk]);
#pragma unroll
      for (int nj = 0; nj < 4; ++nj)
        bfr[nj] = *(const bf16x8*)((const char*)&Blds[cur][0] + boff[nj][kk]);
#pragma unroll
      for (int mi = 0; mi < 2; ++mi)
#pragma unroll
        for (int nj = 0; nj < 4; ++nj)
          acc[mi][nj] = __builtin_amdgcn_mfma_f32_16x16x32_bf16(af[mi], bfr[nj], acc[mi][nj], 0, 0, 0);
    }
    __syncthreads();  // drains vmcnt (staged loads) + lgkm; protects dbuf swap
    cur ^= 1;
  }

#pragma unroll
  for (int mi = 0; mi < 2; ++mi) {
#pragma unroll
    for (int j = 0; j < 4; ++j) {
      int m = mb * BM + wm * 32 + mi * 16 + (lane >> 4) * 4 + j;
      unsigned srow = selb[m];
      float* orow = outb + (size_t)srow * D_;
#pragma unroll
      for (int nj = 0; nj < 4; ++nj) {
        int col = nb * BN + wn * 64 + nj * 16 + (lane & 15);
        orow[col] = acc[mi][nj][j];
      }
    }
  }
}

// ---------------- fallback: reg-staged GEMM + separate copy ----------------
__global__ __launch_bounds__(256) void k_copy_rows(
    const float* __restrict__ x, const unsigned* __restrict__ notsel,
    float* __restrict__ out) {
  const int r = blockIdx.x;
  const int b = r >> 11;
  const unsigned s = notsel[r];
  const size_t off = ((size_t)b * S_ + s) * D_;
  ((float4*)(out + off))[threadIdx.x] = ((const float4*)(x + off))[threadIdx.x];
}

__global__ __launch_bounds__(512) void k_gemm_reg(
    const float* __restrict__ x, const float* __restrict__ w,
    const unsigned* __restrict__ sel, float* __restrict__ out) {
  __shared__ __align__(16) unsigned short Alds[BM * BK];
  __shared__ __align__(16) unsigned short Blds[BN * BK];

  const int bid = blockIdx.x;
  const int b = bid >> 7;
  const int rem = bid & 127;
  const int mb = rem >> 3;
  const int nb = rem & 7;

  const unsigned* selb = sel + b * TOPK_;
  const float* xb = x + (size_t)b * S_ * D_;
  float* outb = out + (size_t)b * S_ * D_;

  const int tid = threadIdx.x;
  const int lane = tid & 63;
  const int wid = tid >> 6;
  const int wm = wid >> 1;
  const int wn = wid & 1;

  const float* asrc[4];
  const float* bsrc[4];
  int srow_[4], sc4_[4];
#pragma unroll
  for (int r = 0; r < 4; ++r) {
    int flat = r * 512 + tid;
    int row = flat >> 4;
    int c4 = flat & 15;
    srow_[r] = row;
    sc4_[r] = c4;
    asrc[r] = xb + (size_t)selb[mb * BM + row] * D_ + c4 * 4;
    bsrc[r] = w + (size_t)(nb * BN + row) * D_ + c4 * 4;
  }

  f32x4 acc[2][4];
#pragma unroll
  for (int i = 0; i < 2; ++i)
#pragma unroll
    for (int j = 0; j < 4; ++j) acc[i][j] = (f32x4)0.0f;

  float4 pa[4], pb[4];
#pragma unroll
  for (int r = 0; r < 4; ++r) {
    pa[r] = *(const float4*)(asrc[r]);
    pb[r] = *(const float4*)(bsrc[r]);
  }

  for (int t = 0; t < NT; ++t) {
#pragma unroll
    for (int r = 0; r < 4; ++r) {
      int row = srow_[r], c4 = sc4_[r];
      int byte = row * 128 + c4 * 8;
      byte ^= (row & 7) << 4;
      *(uint2*)((char*)Alds + byte) = make_uint2(pack2bf16(pa[r].x, pa[r].y), pack2bf16(pa[r].z, pa[r].w));
      *(uint2*)((char*)Blds + byte) = make_uint2(pack2bf16(pb[r].x, pb[r].y), pack2bf16(pb[r].z, pb[r].w));
    }
    __syncthreads();

    if (t + 1 < NT) {
      const int koff = (t + 1) * BK;
#pragma unroll
      for (int r = 0; r < 4; ++r) {
        pa[r] = *(const float4*)(asrc[r] + koff);
        pb[r] = *(const float4*)(bsrc[r] + koff);
      }
    }

#pragma unroll
    for (int kk = 0; kk < 2; ++kk) {
      bf16x8 af[2], bfr[4];
#pragma unroll
      for (int mi = 0; mi < 2; ++mi) {
        int rrow = wm * 32 + mi * 16 + (lane & 15);
        int byte = rrow * 128 + (kk * 32 + (lane >> 4) * 8) * 2;
        byte ^= (rrow & 7) << 4;
        af[mi] = *(const bf16x8*)((const char*)Alds + byte);
      }
#pragma unroll
      for (int nj = 0; nj < 4; ++nj) {
        int rrow = wn * 64 + nj * 16 + (lane & 15);
        int byte = rrow * 128 + (kk * 32 + (lane >> 4) * 8) * 2;
        byte ^= (rrow & 7) << 4;
        bfr[nj] = *(const bf16x8*)((const char*)Blds + byte);
      }
#pragma unroll
      for (int mi = 0; mi < 2; ++mi)
#pragma unroll
        for (int nj = 0; nj < 4; ++nj)
          acc[mi][nj] = __builtin_amdgcn_mfma_f32_16x16x32_bf16(af[mi], bfr[nj], acc[mi][nj], 0, 0, 0);
    }
    __syncthreads();
  }

#pragma unroll
  for (int mi = 0; mi < 2; ++mi) {
#pragma unroll
    for (int j = 0; j < 4; ++j) {
      int m = mb * BM + wm * 32 + mi * 16 + (lane >> 4) * 4 + j;
      unsigned srow = selb[m];
      float* orow = outb + (size_t)srow * D_;
#pragma unroll
      for (int nj = 0; nj < 4; ++nj) {
        int col = nb * BN + wn * 64 + nj * 16 + (lane & 15);
        orow[col] = acc[mi][nj][j];
      }
    }
  }
}

extern "C" void kernel_launch(void* const* d_in, const int* in_sizes, int n_in,
                              void* d_out, int out_size, void* d_ws, size_t ws_size,
                              hipStream_t stream) {
  (void)in_sizes; (void)n_in; (void)out_size;
  const float* x = (const float*)d_in[0];
  const float* wb = (const float*)d_in[1];
  const float* wr = (const float*)d_in[2];
  float* out = (float*)d_out;

  char* ws = (char*)d_ws;
  float* logits = (float*)ws;                                  // 64 KB
  unsigned* sel = (unsigned*)(ws + 65536);                     // 32 KB
  unsigned* notsel = sel + (size_t)B_ * TOPK_;                 // 32 KB -> 128 KB
  unsigned short* xbf = (unsigned short*)(ws + 131072);        // 33.55 MB
  unsigned short* wbf = (unsigned short*)(ws + 131072 + (size_t)B_ * S_ * D_ * 2);  // 2 MB
  const size_t NEED = 131072 + (size_t)B_ * S_ * D_ * 2 + (size_t)D_ * D_ * 2;
  const bool fast = ws_size >= NEED;

  if (fast) {
    k_router_fused<<<B_ * S_ / 4 + D_ * D_ / 1024, 256, 0, stream>>>(x, wr, logits, xbf, wb, wbf);
    k_select<<<B_, 1024, 0, stream>>>(logits, sel, notsel);
    k_gemm_copy<<<COPY_BLOCKS + GEMM_BLOCKS, 512, 0, stream>>>(xbf, wbf, sel, notsel, x, out);
  } else {
    k_router_plain<<<B_ * S_ / 4, 256, 0, stream>>>(x, wr, logits);
    k_select<<<B_, 1024, 0, stream>>>(logits, sel, notsel);
    k_copy_rows<<<B_ * NSEL_, 256, 0, stream>>>(x, notsel, out);
    k_gemm_reg<<<GEMM_BLOCKS, 512, 0, stream>>>(x, wb, sel, out);
  }
}

// Round 12
// 58.359 us; speedup vs baseline: 1.0725x; 1.0694x over previous
//
#include <hip/hip_runtime.h>
#include <hip/hip_bf16.h>
#include <stdint.h>

#define B_ 4
#define S_ 4096
#define D_ 1024
#define TOPK_ 2048
#define NSEL_ (S_ - TOPK_)

#define BM 128
#define BN 128
#define BK 64
#define NT (D_ / BK)       // 16
#define GEMM_BLOCKS (B_ * (TOPK_ / BM) * (D_ / BN))  // 512
#define COPY_BLOCKS (B_ * NSEL_ / 2)                 // 4096 (2 rows each)

typedef __attribute__((ext_vector_type(8))) short bf16x8;
typedef __attribute__((ext_vector_type(4))) float f32x4;

// RNE fp32 -> bf16 pack (two floats -> one u32, low|high)
__device__ __forceinline__ unsigned pack2bf16(float a, float b) {
  unsigned ua = __float_as_uint(a);
  unsigned ub = __float_as_uint(b);
  ua += 0x7fffu + ((ua >> 16) & 1u);
  ub += 0x7fffu + ((ub >> 16) & 1u);
  return (ua >> 16) | (ub & 0xffff0000u);
}

__device__ __forceinline__ unsigned mono_u32(float f) {
  unsigned u = __float_as_uint(f);
  return (u & 0x80000000u) ? ~u : (u | 0x80000000u);
}

__device__ __forceinline__ void gload_lds16(const void* g, void* l) {
  __builtin_amdgcn_global_load_lds(
      (const __attribute__((address_space(1))) void*)g,
      (__attribute__((address_space(3))) void*)l, 16, 0, 0);
}

// ---------------- K1: router logits + x->bf16, tail blocks do W->bf16 ----------------
__global__ __launch_bounds__(256) void k_router_fused(
    const float* __restrict__ x, const float* __restrict__ wr,
    float* __restrict__ logits, unsigned short* __restrict__ xbf,
    const float* __restrict__ wblock, unsigned short* __restrict__ wbf) {
  const int bid = blockIdx.x;
  if (bid >= B_ * S_ / 4) {
    // W fp32 -> bf16: 1024 blocks x 256 thr x 4 floats = D*D
    const int i = (bid - B_ * S_ / 4) * 256 + threadIdx.x;
    float4 v = ((const float4*)wblock)[i];
    *(uint2*)(wbf + (size_t)i * 4) =
        make_uint2(pack2bf16(v.x, v.y), pack2bf16(v.z, v.w));
    return;
  }
  const int lane = threadIdx.x & 63;
  const int token = bid * 4 + (threadIdx.x >> 6);
  const float4* xr = (const float4*)(x + (size_t)token * D_);
  const float4* wrow = (const float4*)wr;
  double acc = 0.0;
#pragma unroll
  for (int i = 0; i < 4; ++i) {
    float4 v = xr[i * 64 + lane];
    float4 w = wrow[i * 64 + lane];
    uint2 p = make_uint2(pack2bf16(v.x, v.y), pack2bf16(v.z, v.w));
    *(uint2*)(xbf + (size_t)token * D_ + i * 256 + lane * 4) = p;
    acc += (double)v.x * (double)w.x + (double)v.y * (double)w.y +
           (double)v.z * (double)w.z + (double)v.w * (double)w.w;
  }
#pragma unroll
  for (int off = 32; off; off >>= 1) acc += __shfl_down(acc, off);
  if (lane == 0) logits[token] = (float)acc;
}

// fallback router (no bf16 staging)
__global__ __launch_bounds__(256) void k_router_plain(
    const float* __restrict__ x, const float* __restrict__ wr,
    float* __restrict__ logits) {
  const int lane = threadIdx.x & 63;
  const int token = blockIdx.x * 4 + (threadIdx.x >> 6);
  const float4* xr = (const float4*)(x + (size_t)token * D_);
  const float4* wrow = (const float4*)wr;
  double acc = 0.0;
#pragma unroll
  for (int i = 0; i < 4; ++i) {
    float4 v = xr[i * 64 + lane];
    float4 w = wrow[i * 64 + lane];
    acc += (double)v.x * (double)w.x + (double)v.y * (double)w.y +
           (double)v.z * (double)w.z + (double)v.w * (double)w.w;
  }
#pragma unroll
  for (int off = 32; off; off >>= 1) acc += __shfl_down(acc, off);
  if (lane == 0) logits[token] = (float)acc;
}

// ---------------- K2: exact top-k via 4-pass radix select ----------------
__global__ __launch_bounds__(1024) void k_select(
    const float* __restrict__ logits, unsigned* __restrict__ sel,
    unsigned* __restrict__ notsel) {
  __shared__ unsigned hist[256];
  __shared__ unsigned bc_digit, bc_need;
  __shared__ unsigned scanbuf[17];

  const int b = blockIdx.x;
  const int tid = threadIdx.x;
  const int lane = tid & 63;
  const int wave = tid >> 6;

  float4 v = *(const float4*)(logits + b * S_ + tid * 4);
  unsigned k0 = mono_u32(v.x), k1 = mono_u32(v.y),
           k2 = mono_u32(v.z), k3 = mono_u32(v.w);

  unsigned prefix = 0, need = TOPK_;
#pragma unroll
  for (int pass = 0; pass < 4; ++pass) {
    const int shift = 24 - pass * 8;
    const unsigned maskhi = pass ? (0xFFFFFFFFu << (shift + 8)) : 0u;
    if (tid < 256) hist[tid] = 0;
    __syncthreads();
    if ((k0 & maskhi) == prefix) atomicAdd(&hist[(k0 >> shift) & 255], 1u);
    if ((k1 & maskhi) == prefix) atomicAdd(&hist[(k1 >> shift) & 255], 1u);
    if ((k2 & maskhi) == prefix) atomicAdd(&hist[(k2 >> shift) & 255], 1u);
    if ((k3 & maskhi) == prefix) atomicAdd(&hist[(k3 >> shift) & 255], 1u);
    __syncthreads();
    if (wave == 0) {
      uint4 h = *(const uint4*)(hist + lane * 4);
      unsigned t = h.x + h.y + h.z + h.w;
      unsigned inc = t;
#pragma unroll
      for (int off = 1; off < 64; off <<= 1) {
        unsigned u = __shfl_up(inc, off);
        if (lane >= off) inc += u;
      }
      unsigned total = __shfl(inc, 63);
      unsigned above = total - inc;
      unsigned a3 = above;
      unsigned a2 = a3 + h.w;
      unsigned a1 = a2 + h.z;
      unsigned a0 = a1 + h.y;
      if (a3 < need && need <= a3 + h.w) { bc_digit = lane * 4 + 3; bc_need = need - a3; }
      else if (a2 < need && need <= a2 + h.z) { bc_digit = lane * 4 + 2; bc_need = need - a2; }
      else if (a1 < need && need <= a1 + h.y) { bc_digit = lane * 4 + 1; bc_need = need - a1; }
      else if (a0 < need && need <= a0 + h.x) { bc_digit = lane * 4 + 0; bc_need = need - a0; }
    }
    __syncthreads();
    prefix |= bc_digit << shift;
    need = bc_need;
  }

  const unsigned V = prefix;
  const unsigned fneed = need;

  unsigned packed = 0;
  unsigned pk_excl0, pk_excl1, pk_excl2, pk_excl3;
  pk_excl0 = packed; if (k0 > V) packed += 1u << 16; else if (k0 == V) packed += 1u;
  pk_excl1 = packed; if (k1 > V) packed += 1u << 16; else if (k1 == V) packed += 1u;
  pk_excl2 = packed; if (k2 > V) packed += 1u << 16; else if (k2 == V) packed += 1u;
  pk_excl3 = packed; if (k3 > V) packed += 1u << 16; else if (k3 == V) packed += 1u;

  unsigned inc = packed;
#pragma unroll
  for (int off = 1; off < 64; off <<= 1) {
    unsigned u = __shfl_up(inc, off);
    if (lane >= off) inc += u;
  }
  if (lane == 63) scanbuf[wave] = inc;
  __syncthreads();
  if (tid < 16) {
    unsigned t = scanbuf[tid];
    unsigned winc = t;
#pragma unroll
    for (int off = 1; off < 16; off <<= 1) {
      unsigned u = __shfl_up(winc, off);
      if (tid >= off) winc += u;
    }
    scanbuf[tid] = winc - t;
    if (tid == 15) scanbuf[16] = winc;
  }
  __syncthreads();
  const unsigned base = scanbuf[wave] + (inc - packed);
  const unsigned G_total = scanbuf[16] >> 16;

  unsigned* selb = sel + b * TOPK_;
  unsigned* notb = notsel + b * NSEL_;
#pragma unroll
  for (int i = 0; i < 4; ++i) {
    unsigned ki = (i == 0) ? k0 : (i == 1) ? k1 : (i == 2) ? k2 : k3;
    unsigned pe = (i == 0) ? pk_excl0 : (i == 1) ? pk_excl1 : (i == 2) ? pk_excl2 : pk_excl3;
    unsigned s = tid * 4 + i;
    unsigned gtE = (base + pe) >> 16;
    unsigned eqE = (base + pe) & 0xFFFFu;
    if (ki > V) {
      selb[gtE] = s;
    } else if (ki == V && eqE < fneed) {
      selb[G_total + eqE] = s;
    } else {
      unsigned eqTaken = (eqE < fneed) ? eqE : fneed;
      notb[s - gtE - eqTaken] = s;
    }
  }
}

// ---------------- K3 (fast): fused GEMM + complement-row copy (round-4 exact) ----------------
// blocks [0, GEMM_BLOCKS): bf16 gathered GEMM + scatter (dbuf, gload_lds,
//   XOR-swizzled LDS with inverse-swizzled source, XCD-aware remap).
// blocks [GEMM_BLOCKS, +COPY_BLOCKS): copy 2 non-selected rows each; these
//   backfill CU slots as GEMM blocks retire (overlapped tail).
__global__ __launch_bounds__(512) void k_gemm_copy(
    const unsigned short* __restrict__ xbf, const unsigned short* __restrict__ wbf,
    const unsigned* __restrict__ sel, const unsigned* __restrict__ notsel,
    const float* __restrict__ x, float* __restrict__ out) {
  __shared__ __align__(16) unsigned short Alds[2][BM * BK];
  __shared__ __align__(16) unsigned short Blds[2][BN * BK];

  const int bid = blockIdx.x;
  const int tid = threadIdx.x;

  if (bid >= GEMM_BLOCKS) {
    // ---- copy path: row r = 2*(bid-GEMM_BLOCKS) + (tid>>8), col16 = tid&255
    const int r = (bid - GEMM_BLOCKS) * 2 + (tid >> 8);  // 0..B_*NSEL_-1
    const int b = r >> 11;                                // NSEL_ == 2048
    const unsigned s = notsel[r];
    const size_t off = ((size_t)b * S_ + s) * D_;
    ((float4*)(out + off))[tid & 255] = ((const float4*)(x + off))[tid & 255];
    return;
  }

  // ---- GEMM path
  // XCD-aware swizzle: XCD = bid&7 owns 8 contiguous M-panels x all 8 N-tiles.
  const int gtile = (bid & 7) * 64 + (bid >> 3);
  const int mtile = gtile >> 3;
  const int nb = gtile & 7;
  const int b = mtile >> 4;
  const int mb = mtile & 15;

  const unsigned* selb = sel + b * TOPK_;
  const unsigned short* xb = xbf + (size_t)b * S_ * D_;
  float* outb = out + (size_t)b * S_ * D_;

  const int lane = tid & 63;
  const int wid = tid >> 6;
  const int wm = wid >> 1;
  const int wn = wid & 1;

  const unsigned short* asrc[2];
  const unsigned short* bsrc[2];
  unsigned ldsoff[2];
#pragma unroll
  for (int r = 0; r < 2; ++r) {
    int chunk = r * 512 + tid;
    int row = chunk >> 3, c16 = chunk & 7;
    int sw = c16 ^ (row & 7);  // inverse swizzle on source, linear LDS dest
    asrc[r] = xb + (size_t)selb[mb * BM + row] * D_ + sw * 8;
    bsrc[r] = wbf + (size_t)(nb * BN + row) * D_ + sw * 8;
    ldsoff[r] = chunk * 16;
  }

  unsigned aoff[2][2], boff[4][2];
#pragma unroll
  for (int mi = 0; mi < 2; ++mi)
#pragma unroll
    for (int kk = 0; kk < 2; ++kk) {
      int rrow = wm * 32 + mi * 16 + (lane & 15);
      int byte = rrow * 128 + kk * 64 + (lane >> 4) * 16;
      aoff[mi][kk] = byte ^ ((rrow & 7) << 4);
    }
#pragma unroll
  for (int nj = 0; nj < 4; ++nj)
#pragma unroll
    for (int kk = 0; kk < 2; ++kk) {
      int rrow = wn * 64 + nj * 16 + (lane & 15);
      int byte = rrow * 128 + kk * 64 + (lane >> 4) * 16;
      boff[nj][kk] = byte ^ ((rrow & 7) << 4);
    }

  f32x4 acc[2][4];
#pragma unroll
  for (int i = 0; i < 2; ++i)
#pragma unroll
    for (int j = 0; j < 4; ++j) acc[i][j] = (f32x4)0.0f;

#pragma unroll
  for (int r = 0; r < 2; ++r) {
    gload_lds16(asrc[r], (char*)&Alds[0][0] + ldsoff[r]);
    gload_lds16(bsrc[r], (char*)&Blds[0][0] + ldsoff[r]);
  }
  __syncthreads();

  int cur = 0;
  for (int t = 0; t < NT; ++t) {
    if (t + 1 < NT) {
      const int koff = (t + 1) * BK;
#pragma unroll
      for (int r = 0; r < 2; ++r) {
        gload_lds16(asrc[r] + koff, (char*)&Alds[cur ^ 1][0] + ldsoff[r]);
        gload_lds16(bsrc[r] + koff, (char*)&Blds[cur ^ 1][0] + ldsoff[r]);
      }
    }
#pragma unroll
    for (int kk = 0; kk < 2; ++kk) {
      bf16x8 af[2], bfr[4];
#pragma unroll
      for (int mi = 0; mi < 2; ++mi)
        af[mi] = *(const bf16x8*)((const char*)&Alds[cur][0] + aoff[mi][kk]);
#pragma unroll
      for (int nj = 0; nj < 4; ++nj)
        bfr[nj] = *(const bf16x8*)((const char*)&Blds[cur][0] + boff[nj][kk]);
#pragma unroll
      for (int mi = 0; mi < 2; ++mi)
#pragma unroll
        for (int nj = 0; nj < 4; ++nj)
          acc[mi][nj] = __builtin_amdgcn_mfma_f32_16x16x32_bf16(af[mi], bfr[nj], acc[mi][nj], 0, 0, 0);
    }
    __syncthreads();  // drains vmcnt (staged loads) + lgkm; protects dbuf swap
    cur ^= 1;
  }

#pragma unroll
  for (int mi = 0; mi < 2; ++mi) {
#pragma unroll
    for (int j = 0; j < 4; ++j) {
      int m = mb * BM + wm * 32 + mi * 16 + (lane >> 4) * 4 + j;
      unsigned srow = selb[m];
      float* orow = outb + (size_t)srow * D_;
#pragma unroll
      for (int nj = 0; nj < 4; ++nj) {
        int col = nb * BN + wn * 64 + nj * 16 + (lane & 15);
        orow[col] = acc[mi][nj][j];
      }
    }
  }
}

// ---------------- fallback: reg-staged GEMM + separate copy ----------------
__global__ __launch_bounds__(256) void k_copy_rows(
    const float* __restrict__ x, const unsigned* __restrict__ notsel,
    float* __restrict__ out) {
  const int r = blockIdx.x;
  const int b = r >> 11;
  const unsigned s = notsel[r];
  const size_t off = ((size_t)b * S_ + s) * D_;
  ((float4*)(out + off))[threadIdx.x] = ((const float4*)(x + off))[threadIdx.x];
}

__global__ __launch_bounds__(512) void k_gemm_reg(
    const float* __restrict__ x, const float* __restrict__ w,
    const unsigned* __restrict__ sel, float* __restrict__ out) {
  __shared__ __align__(16) unsigned short Alds[BM * BK];
  __shared__ __align__(16) unsigned short Blds[BN * BK];

  const int bid = blockIdx.x;
  const int b = bid >> 7;
  const int rem = bid & 127;
  const int mb = rem >> 3;
  const int nb = rem & 7;

  const unsigned* selb = sel + b * TOPK_;
  const float* xb = x + (size_t)b * S_ * D_;
  float* outb = out + (size_t)b * S_ * D_;

  const int tid = threadIdx.x;
  const int lane = tid & 63;
  const int wid = tid >> 6;
  const int wm = wid >> 1;
  const int wn = wid & 1;

  const float* asrc[4];
  const float* bsrc[4];
  int srow_[4], sc4_[4];
#pragma unroll
  for (int r = 0; r < 4; ++r) {
    int flat = r * 512 + tid;
    int row = flat >> 4;
    int c4 = flat & 15;
    srow_[r] = row;
    sc4_[r] = c4;
    asrc[r] = xb + (size_t)selb[mb * BM + row] * D_ + c4 * 4;
    bsrc[r] = w + (size_t)(nb * BN + row) * D_ + c4 * 4;
  }

  f32x4 acc[2][4];
#pragma unroll
  for (int i = 0; i < 2; ++i)
#pragma unroll
    for (int j = 0; j < 4; ++j) acc[i][j] = (f32x4)0.0f;

  float4 pa[4], pb[4];
#pragma unroll
  for (int r = 0; r < 4; ++r) {
    pa[r] = *(const float4*)(asrc[r]);
    pb[r] = *(const float4*)(bsrc[r]);
  }

  for (int t = 0; t < NT; ++t) {
#pragma unroll
    for (int r = 0; r < 4; ++r) {
      int row = srow_[r], c4 = sc4_[r];
      int byte = row * 128 + c4 * 8;
      byte ^= (row & 7) << 4;
      *(uint2*)((char*)Alds + byte) = make_uint2(pack2bf16(pa[r].x, pa[r].y), pack2bf16(pa[r].z, pa[r].w));
      *(uint2*)((char*)Blds + byte) = make_uint2(pack2bf16(pb[r].x, pb[r].y), pack2bf16(pb[r].z, pb[r].w));
    }
    __syncthreads();

    if (t + 1 < NT) {
      const int koff = (t + 1) * BK;
#pragma unroll
      for (int r = 0; r < 4; ++r) {
        pa[r] = *(const float4*)(asrc[r] + koff);
        pb[r] = *(const float4*)(bsrc[r] + koff);
      }
    }

#pragma unroll
    for (int kk = 0; kk < 2; ++kk) {
      bf16x8 af[2], bfr[4];
#pragma unroll
      for (int mi = 0; mi < 2; ++mi) {
        int rrow = wm * 32 + mi * 16 + (lane & 15);
        int byte = rrow * 128 + (kk * 32 + (lane >> 4) * 8) * 2;
        byte ^= (rrow & 7) << 4;
        af[mi] = *(const bf16x8*)((const char*)Alds + byte);
      }
#pragma unroll
      for (int nj = 0; nj < 4; ++nj) {
        int rrow = wn * 64 + nj * 16 + (lane & 15);
        int byte = rrow * 128 + (kk * 32 + (lane >> 4) * 8) * 2;
        byte ^= (rrow & 7) << 4;
        bfr[nj] = *(const bf16x8*)((const char*)Blds + byte);
      }
#pragma unroll
      for (int mi = 0; mi < 2; ++mi)
#pragma unroll
        for (int nj = 0; nj < 4; ++nj)
          acc[mi][nj] = __builtin_amdgcn_mfma_f32_16x16x32_bf16(af[mi], bfr[nj], acc[mi][nj], 0, 0, 0);
    }
    __syncthreads();
  }

#pragma unroll
  for (int mi = 0; mi < 2; ++mi) {
#pragma unroll
    for (int j = 0; j < 4; ++j) {
      int m = mb * BM + wm * 32 + mi * 16 + (lane >> 4) * 4 + j;
      unsigned srow = selb[m];
      float* orow = outb + (size_t)srow * D_;
#pragma unroll
      for (int nj = 0; nj < 4; ++nj) {
        int col = nb * BN + wn * 64 + nj * 16 + (lane & 15);
        orow[col] = acc[mi][nj][j];
      }
    }
  }
}

extern "C" void kernel_launch(void* const* d_in, const int* in_sizes, int n_in,
                              void* d_out, int out_size, void* d_ws, size_t ws_size,
                              hipStream_t stream) {
  (void)in_sizes; (void)n_in; (void)out_size;
  const float* x = (const float*)d_in[0];
  const float* wb = (const float*)d_in[1];
  const float* wr = (const float*)d_in[2];
  float* out = (float*)d_out;

  char* ws = (char*)d_ws;
  float* logits = (float*)ws;                                  // 64 KB
  unsigned* sel = (unsigned*)(ws + 65536);                     // 32 KB
  unsigned* notsel = sel + (size_t)B_ * TOPK_;                 // 32 KB -> 128 KB
  unsigned short* xbf = (unsigned short*)(ws + 131072);        // 33.55 MB
  unsigned short* wbf = (unsigned short*)(ws + 131072 + (size_t)B_ * S_ * D_ * 2);  // 2 MB
  const size_t NEED = 131072 + (size_t)B_ * S_ * D_ * 2 + (size_t)D_ * D_ * 2;
  const bool fast = ws_size >= NEED;

  if (fast) {
    k_router_fused<<<B_ * S_ / 4 + D_ * D_ / 1024, 256, 0, stream>>>(x, wr, logits, xbf, wb, wbf);
    k_select<<<B_, 1024, 0, stream>>>(logits, sel, notsel);
    k_gemm_copy<<<GEMM_BLOCKS + COPY_BLOCKS, 512, 0, stream>>>(xbf, wbf, sel, notsel, x, out);
  } else {
    k_router_plain<<<B_ * S_ / 4, 256, 0, stream>>>(x, wr, logits);
    k_select<<<B_, 1024, 0, stream>>>(logits, sel, notsel);
    k_copy_rows<<<B_ * NSEL_, 256, 0, stream>>>(x, notsel, out);
    k_gemm_reg<<<GEMM_BLOCKS, 512, 0, stream>>>(x, wb, sel, out);
  }
}